// Round 1
// 396.466 us; speedup vs baseline: 1.0274x; 1.0274x over previous
//
#include <hip/hip_runtime.h>
#include <hip/hip_bf16.h>
#include <cstdint>

// Problem constants: B=8, L=4096, D=768, Y=2048
#define BB 8
#define LL 4096
#define DD 768
#define YY 2048

typedef unsigned short u16;
typedef __bf16 bf16x8 __attribute__((ext_vector_type(8)));
typedef __bf16 bf16x2 __attribute__((ext_vector_type(2)));
typedef float f32x4 __attribute__((ext_vector_type(4)));

__device__ __forceinline__ u16 f2bf(float f) {
    uint32_t u = __float_as_uint(f);
    u += 0x7fffu + ((u >> 16) & 1u);   // RNE
    return (u16)(u >> 16);
}

__device__ __forceinline__ uint32_t pkbf(float a, float b) {
#if __has_builtin(__builtin_amdgcn_cvt_pk_bf16_f32)
    bf16x2 p = __builtin_amdgcn_cvt_pk_bf16_f32(a, b);
    return __builtin_bit_cast(uint32_t, p);
#else
    return (uint32_t)f2bf(a) | ((uint32_t)f2bf(b) << 16);
#endif
}

#define GLL(src, dst) \
    __builtin_amdgcn_global_load_lds((const __attribute__((address_space(1))) unsigned int*)(src), \
                                     (__attribute__((address_space(3))) unsigned int*)(dst), 16, 0, 0)

// ---------------- cast Y*D weight matrix (U or fw) to bf16 ----------------
__global__ __launch_bounds__(256) void cast_w_k(const float* __restrict__ W, u16* __restrict__ W16) {
    int i = blockIdx.x * 256 + threadIdx.x;          // one float4 per thread
    float4 v = ((const float4*)W)[i];
    uint2 h;
    h.x = pkbf(v.x, v.y); h.y = pkbf(v.z, v.w);
    ((uint2*)W16)[i] = h;
}

// ---------------- cast x (B*L*D) to bf16, pure elementwise ----------------
__global__ __launch_bounds__(256) void cast_x_k(const float* __restrict__ x, u16* __restrict__ x16) {
    int i = blockIdx.x * 256 + threadIdx.x;          // one float4 per thread
    float4 v = ((const float4*)x)[i];
    uint2 h;
    h.x = pkbf(v.x, v.y); h.y = pkbf(v.z, v.w);
    ((uint2*)x16)[i] = h;
}

// ---------------- FUSED kernel: S=U.x^T and G=fw.x^T, epilogue sum exp(S), exp(S)*G ------
// y[b,r] = sum_l exp(att[r,l]) * G[r,l] / rowsum[r]   (summation order swapped).
// R9: BM=128(l) x BN=64(y), 270 us. R10: L2-resident-weights block order -> 261 us.
// R11: counted-vmcnt pipeline (T3/T4). The old __syncthreads 2-phase loop drained
// vmcnt(0) at every barrier -> each tile's GLLs only had the ~180-cycle compute phase
// to land (L2/HBM latency 200-900 cyc) -> MfmaUtil stuck at 36% (m97-structure ceiling).
// Now: 3 LDS buffers, 2-tile-deep prefetch, raw s_barrier + s_waitcnt vmcnt(8) in
// steady state (4 GLLs/tile/wave; tiles t+1,t+2 stay in flight ACROSS barriers),
// lgkmcnt(0) before the buffer-release barrier, setprio(1) around the MFMA cluster.
__global__ __launch_bounds__(256, 3) void fused_k(const u16* __restrict__ Xg, const u16* __restrict__ Ug,
                                                  const u16* __restrict__ Wg,
                                                  float* __restrict__ rowsum, float* __restrict__ ynum) {
    __shared__ u16 As[3 * 4096];      // x tile: 128 l-rows x 32 k (3-buf, 24 KB)
    __shared__ u16 Us[3 * 2048];      // U tile: 64 y-rows x 32 k (3-buf, 12 KB)
    __shared__ u16 Ws[3 * 2048];      // fw tile (12 KB)
    const int id = blockIdx.x;
    const int b = id & 7;             // batch pinned per XCD (%8 round-robin heuristic)
    const int r = id >> 3;            // 0..1023
    const int yhalf = r >> 9;         // 0..1   (outer: U/fw half swapped once)
    const int q = r & 511;
    const int mblk = q >> 4;          // 0..31  (middle: x-tile advances, U/fw-half L2-hot)
    const int nblk = (yhalf << 4) + (q & 15);   // inner 16 y-blocks share one x-tile
    const u16* A = Xg + (size_t)b * LL * DD;
    rowsum += (size_t)b * YY;
    ynum   += (size_t)b * YY;
    const int m0 = mblk * 128;        // l
    const int n0 = nblk * 64;         // y
    const int t = threadIdx.x;
    const int lane = t & 63;
    const int wave = t >> 6;
    const int wm = (wave >> 1) * 64;  // l-offset of wave
    const int wn = (wave & 1) * 32;   // y-offset of wave
    const int ln = lane & 15;
    const int qd = lane >> 4;
    const int swz = (qd ^ ((ln >> 1) & 3)) * 8;   // conflict-free ds_read_b128 swizzle

    const int kq0 = (t & 3) ^ ((t >> 3) & 3);
    const u16* Ab0 = A + (size_t)(m0 + (t >> 2)) * DD + kq0 * 8;       // rows 0..63
    const u16* Ab1 = A + (size_t)(m0 + (t >> 2) + 64) * DD + kq0 * 8;  // rows 64..127
    const u16* Ub0 = Ug + (size_t)(n0 + (t >> 2)) * DD + kq0 * 8;      // 64 rows, 1 GLL
    const u16* Wb0 = Wg + (size_t)(n0 + (t >> 2)) * DD + kq0 * 8;
    const int c0 = t * 8, c1 = (t + 256) * 8;

    f32x4 aS[4][2] = {};
    f32x4 aG[4][2] = {};
    const int au = (wm + ln) * 32 + swz;
    const int bu = (wn + ln) * 32 + swz;

// stage one K-tile (4 GLL instructions per wave) into buffer bi, advance pointers
#define STAGE(bi)                                                       \
    {                                                                   \
        GLL(Ab0, As + (bi) * 4096 + c0);                                \
        GLL(Ab1, As + (bi) * 4096 + c1);                                \
        GLL(Ub0, Us + (bi) * 2048 + c0);                                \
        GLL(Wb0, Ws + (bi) * 2048 + c0);                                \
        Ab0 += 32; Ab1 += 32; Ub0 += 32; Wb0 += 32;                     \
    }

#define COMPUTE(pa, pw)                                                             \
    {                                                                               \
        bf16x8 af[4], bfU[2], bfW[2];                                               \
        _Pragma("unroll")                                                           \
        for (int i = 0; i < 4; ++i)                                                 \
            af[i] = *(const bf16x8*)(As + (pa) + au + i * 512);                     \
        _Pragma("unroll")                                                           \
        for (int j = 0; j < 2; ++j) {                                               \
            bfU[j] = *(const bf16x8*)(Us + (pw) + bu + j * 512);                    \
            bfW[j] = *(const bf16x8*)(Ws + (pw) + bu + j * 512);                    \
        }                                                                           \
        __builtin_amdgcn_s_setprio(1);                                              \
        _Pragma("unroll")                                                           \
        for (int i = 0; i < 4; ++i)                                                 \
            _Pragma("unroll")                                                       \
            for (int j = 0; j < 2; ++j) {                                           \
                aS[i][j] = __builtin_amdgcn_mfma_f32_16x16x32_bf16(af[i], bfU[j], aS[i][j], 0, 0, 0); \
                aG[i][j] = __builtin_amdgcn_mfma_f32_16x16x32_bf16(af[i], bfW[j], aG[i][j], 0, 0, 0); \
            }                                                                       \
        __builtin_amdgcn_s_setprio(0);                                              \
    }

#define WAITV(n) asm volatile("s_waitcnt vmcnt(" #n ")" ::: "memory")
#define WAITL    asm volatile("s_waitcnt lgkmcnt(0)" ::: "memory")
#define BAR      __builtin_amdgcn_s_barrier()

    // prologue: tiles 0,1 in flight (8 outstanding GLLs per wave)
    STAGE(0)
    STAGE(1)

    // main loop: kt = 0..20 (7 x 3, buffers cycle 0,1,2; stage kt+2 each step).
    // WAITV(8): my 4 oldest outstanding loads (= tile kt) are done; tiles kt+1,kt+2
    // (8 loads) remain in flight across both barriers.  B1: everyone's tile-kt data
    // is in LDS.  WAITL+B2: everyone's ds_reads of this buffer drained -> buffer free.
    for (int i = 0; i < 7; ++i) {
        STAGE(2) WAITV(8); BAR; COMPUTE(0, 0)          WAITL; BAR;
        STAGE(0) WAITV(8); BAR; COMPUTE(4096, 2048)    WAITL; BAR;
        STAGE(1) WAITV(8); BAR; COMPUTE(8192, 4096)    WAITL; BAR;
    }
    // kt=21: last stage (tile 23 -> buf2)
    STAGE(2) WAITV(8); BAR; COMPUTE(0, 0)          WAITL; BAR;
    // kt=22: drain to 4 (tile 23 still in flight)
    WAITV(4); BAR; COMPUTE(4096, 2048)             WAITL; BAR;
    // kt=23: final tile
    WAITV(0); BAR; COMPUTE(8192, 4096)
#undef COMPUTE
#undef STAGE

    // epilogue: acc[i][j][rr] -> (y = n0+wn+j*16+ln, l = m0+wm+i*16+qd*4+rr)
    #pragma unroll
    for (int j = 0; j < 2; ++j) {
        const int y = n0 + wn + j * 16 + ln;
        float rs = 0.f, ys = 0.f;
        #pragma unroll
        for (int i = 0; i < 4; ++i) {
            #pragma unroll
            for (int rr = 0; rr < 4; ++rr) {
                float e = __expf(aS[i][j][rr]);
                rs += e;
                ys += e * aG[i][j][rr];
            }
        }
        rs += __shfl_xor(rs, 16, 64);  ys += __shfl_xor(ys, 16, 64);
        rs += __shfl_xor(rs, 32, 64);  ys += __shfl_xor(ys, 32, 64);
        if (qd == 0) {
            atomicAdd(&rowsum[y], rs);
            atomicAdd(&ynum[y], ys);
        }
    }
}

// -------- finalize: y = ynum/rowsum + bias (writeback), CE loss over y --------
// R11: one block per batch (8 blocks) instead of a single latency-bound block;
// partial NLLs combined via atomicAdd into out0 (zeroed by memset in launch).
__global__ __launch_bounds__(256) void ce_loss_k(const float* __restrict__ ynum,
                                                 const float* __restrict__ rowsum,
                                                 const float* __restrict__ fb,
                                                 const int* __restrict__ tgt,
                                                 float* __restrict__ out0,
                                                 float* __restrict__ yv) {
    __shared__ float smx[4], ssum[4], stv[4];
    const int b = blockIdx.x;
    const int t = threadIdx.x;
    const int wave = t >> 6, lane = t & 63;
    const float* yn = ynum + b * YY;
    const float* rsm = rowsum + b * YY;
    float* row = yv + b * YY;
    const int tg = tgt[b];
    float v[8];
    float mx = -3.0e38f;
    float tv = 0.f;
    #pragma unroll
    for (int i = 0; i < 8; ++i) {
        const int idx = t + 256 * i;
        v[i] = yn[idx] / rsm[idx] + fb[idx];
        row[idx] = v[i];                    // write final y
        mx = fmaxf(mx, v[i]);
        if (idx == tg) tv = v[i];
    }
    // block-reduce max
    #pragma unroll
    for (int o = 32; o; o >>= 1) mx = fmaxf(mx, __shfl_xor(mx, o, 64));
    if (lane == 0) smx[wave] = mx;
    __syncthreads();
    mx = fmaxf(fmaxf(smx[0], smx[1]), fmaxf(smx[2], smx[3]));
    float s = 0.f;
    #pragma unroll
    for (int i = 0; i < 8; ++i) s += __expf(v[i] - mx);
    #pragma unroll
    for (int o = 32; o; o >>= 1) { s += __shfl_xor(s, o, 64); tv += __shfl_xor(tv, o, 64); }
    if (lane == 0) { ssum[wave] = s; stv[wave] = tv; }
    __syncthreads();
    if (t == 0) {
        float st = ssum[0] + ssum[1] + ssum[2] + ssum[3];
        float tt = stv[0] + stv[1] + stv[2] + stv[3];
        atomicAdd(out0, (mx + logf(st) - tt) * 0.125f);
    }
}

extern "C" void kernel_launch(void* const* d_in, const int* in_sizes, int n_in,
                              void* d_out, int out_size, void* d_ws, size_t ws_size,
                              hipStream_t stream) {
    const float* x   = (const float*)d_in[0];   // (B,L,D)
    const float* Uw  = (const float*)d_in[1];   // (Y,D)
    const float* fw  = (const float*)d_in[2];   // (Y,D)
    const float* fb  = (const float*)d_in[3];   // (Y,)
    const int*   tgt = (const int*)d_in[4];     // (B,)
    float* out = (float*)d_out;                 // [loss, y(B*Y)]

    char* ws = (char*)d_ws;
    u16*  x16  = (u16*)(ws);                          // B*L*D bf16 = 50,331,648 B
    u16*  U16  = (u16*)(ws + 50331648);               // Y*D bf16   =  3,145,728 B
    u16*  fw16 = (u16*)(ws + 53477376);               // Y*D bf16   =  3,145,728 B
    float* rowsum = (float*)(ws + 56623104);          // B*Y fp32   =     65,536 B
    float* ynum   = (float*)(ws + 56688640);          // B*Y fp32   =     65,536 B

    hipMemsetAsync(rowsum, 0, 2 * (size_t)BB * YY * sizeof(float), stream);  // rowsum+ynum
    hipMemsetAsync(out, 0, sizeof(float), stream);                           // loss accumulator
    cast_w_k<<<1536, 256, 0, stream>>>(Uw, U16);
    cast_w_k<<<1536, 256, 0, stream>>>(fw, fw16);
    cast_x_k<<<(BB * LL * DD) / 1024, 256, 0, stream>>>(x, x16);

    // Fused S/G GEMM + exp + reductions: 8192 blocks, L2-resident-weights order
    fused_k<<<(LL / 128) * (YY / 64) * BB, 256, 0, stream>>>(x16, U16, fw16, rowsum, ynum);

    ce_loss_k<<<BB, 256, 0, stream>>>(ynum, rowsum, fb, tgt, out, out + 1);
}

// Round 2
// 372.915 us; speedup vs baseline: 1.0923x; 1.0632x over previous
//
#include <hip/hip_runtime.h>
#include <hip/hip_bf16.h>
#include <cstdint>

// Problem constants: B=8, L=4096, D=768, Y=2048
#define BB 8
#define LL 4096
#define DD 768
#define YY 2048

typedef unsigned short u16;
typedef __bf16 bf16x8 __attribute__((ext_vector_type(8)));
typedef __bf16 bf16x2 __attribute__((ext_vector_type(2)));
typedef float f32x4 __attribute__((ext_vector_type(4)));

__device__ __forceinline__ u16 f2bf(float f) {
    uint32_t u = __float_as_uint(f);
    u += 0x7fffu + ((u >> 16) & 1u);   // RNE
    return (u16)(u >> 16);
}

__device__ __forceinline__ uint32_t pkbf(float a, float b) {
#if __has_builtin(__builtin_amdgcn_cvt_pk_bf16_f32)
    bf16x2 p = __builtin_amdgcn_cvt_pk_bf16_f32(a, b);
    return __builtin_bit_cast(uint32_t, p);
#else
    return (uint32_t)f2bf(a) | ((uint32_t)f2bf(b) << 16);
#endif
}

#define GLL(src, dst) \
    __builtin_amdgcn_global_load_lds((const __attribute__((address_space(1))) unsigned int*)(src), \
                                     (__attribute__((address_space(3))) unsigned int*)(dst), 16, 0, 0)

// ---------------- cast Y*D weight matrix (U or fw) to bf16 ----------------
__global__ __launch_bounds__(256) void cast_w_k(const float* __restrict__ W, u16* __restrict__ W16) {
    int i = blockIdx.x * 256 + threadIdx.x;          // one float4 per thread
    float4 v = ((const float4*)W)[i];
    uint2 h;
    h.x = pkbf(v.x, v.y); h.y = pkbf(v.z, v.w);
    ((uint2*)W16)[i] = h;
}

// ---------------- cast x (B*L*D) to bf16, pure elementwise ----------------
__global__ __launch_bounds__(256) void cast_x_k(const float* __restrict__ x, u16* __restrict__ x16) {
    int i = blockIdx.x * 256 + threadIdx.x;          // one float4 per thread
    float4 v = ((const float4*)x)[i];
    uint2 h;
    h.x = pkbf(v.x, v.y); h.y = pkbf(v.z, v.w);
    ((uint2*)x16)[i] = h;
}

// ---------------- FUSED kernel: S=U.x^T and G=fw.x^T, epilogue sum exp(S), exp(S)*G ------
// y[b,r] = sum_l exp(att[r,l]) * G[r,l] / rowsum[r]   (summation order swapped).
// R10: 2-phase sync, BM=128 x BN=64 -> 261 us, MfmaUtil 36%.
// R11: counted-vmcnt 3-buf pipeline -> NEUTRAL (265 us). Post-mortem: global latency
// was already hidden by cross-block TLP; kernel is phase-granularity-bound: per phase
// only 16 MFMA (~80 cyc) vs LDS latency + 2 block barriers; LDS intensity 32 FLOP/B.
// R12: per-wave tile 64x32 -> 64x64 (block 128l x 128y, 4 waves 2x2).
//   - LDS bytes/FLOP x0.75 (reads AND gll-writes); 32 MFMA per phase per wave.
//   - acc 128 f32 + frags ~48 -> ~210 VGPR -> 2 waves/SIMD (VGPR-bound, so 3-buf
//     72 KB LDS costs nothing: 2 blocks/CU either way).
//   - same swizzle, same counted-vmcnt skeleton (6 GLL/stage -> steady wait vmcnt(12)),
//     same L2-resident-weights block order (8 inner y-blocks = 3.1 MB per XCD).
__global__ __launch_bounds__(256, 2) void fused_k(const u16* __restrict__ Xg, const u16* __restrict__ Ug,
                                                  const u16* __restrict__ Wg,
                                                  float* __restrict__ rowsum, float* __restrict__ ynum) {
    __shared__ u16 As[3 * 4096];      // x tile: 128 l-rows x 32 k (3-buf, 24 KB)
    __shared__ u16 Us[3 * 4096];      // U tile: 128 y-rows x 32 k (3-buf, 24 KB)
    __shared__ u16 Ws[3 * 4096];      // fw tile (24 KB)
    const int id = blockIdx.x;
    const int b = id & 7;             // batch pinned per XCD (%8 round-robin heuristic)
    const int r = id >> 3;            // 0..511
    const int yhalf = r >> 8;         // 0..1   (outer: U/fw half swapped once)
    const int q = r & 255;
    const int mblk = q >> 3;          // 0..31  (middle: x-tile advances, U/fw-half L2-hot)
    const int nblk = (yhalf << 3) + (q & 7);    // inner 8 y-blocks share one x-tile
    const u16* A = Xg + (size_t)b * LL * DD;
    rowsum += (size_t)b * YY;
    ynum   += (size_t)b * YY;
    const int m0 = mblk * 128;        // l
    const int n0 = nblk * 128;        // y
    const int t = threadIdx.x;
    const int lane = t & 63;
    const int wave = t >> 6;
    const int wm = (wave >> 1) * 64;  // l-offset of wave
    const int wn = (wave & 1) * 64;   // y-offset of wave
    const int ln = lane & 15;
    const int qd = lane >> 4;
    const int swz = (qd ^ ((ln >> 1) & 3)) * 8;   // conflict-free ds_read_b128 swizzle

    const int kq0 = (t & 3) ^ ((t >> 3) & 3);
    const u16* Ab0 = A + (size_t)(m0 + (t >> 2)) * DD + kq0 * 8;       // l rows 0..63
    const u16* Ab1 = A + (size_t)(m0 + (t >> 2) + 64) * DD + kq0 * 8;  // l rows 64..127
    const u16* Ub0 = Ug + (size_t)(n0 + (t >> 2)) * DD + kq0 * 8;      // y rows 0..63
    const u16* Ub1 = Ug + (size_t)(n0 + (t >> 2) + 64) * DD + kq0 * 8; // y rows 64..127
    const u16* Wb0 = Wg + (size_t)(n0 + (t >> 2)) * DD + kq0 * 8;
    const u16* Wb1 = Wg + (size_t)(n0 + (t >> 2) + 64) * DD + kq0 * 8;
    const int c0 = t * 8, c1 = (t + 256) * 8;

    f32x4 aS[4][4] = {};
    f32x4 aG[4][4] = {};
    const int au = (wm + ln) * 32 + swz;
    const int bu = (wn + ln) * 32 + swz;

// stage one K-tile (6 GLL instructions per thread) into buffer bi, advance pointers
#define STAGE(bi)                                                       \
    {                                                                   \
        GLL(Ab0, As + (bi) * 4096 + c0);                                \
        GLL(Ab1, As + (bi) * 4096 + c1);                                \
        GLL(Ub0, Us + (bi) * 4096 + c0);                                \
        GLL(Ub1, Us + (bi) * 4096 + c1);                                \
        GLL(Wb0, Ws + (bi) * 4096 + c0);                                \
        GLL(Wb1, Ws + (bi) * 4096 + c1);                                \
        Ab0 += 32; Ab1 += 32; Ub0 += 32; Ub1 += 32; Wb0 += 32; Wb1 += 32; \
    }

#define COMPUTE(p)                                                                  \
    {                                                                               \
        bf16x8 af[4], bfU[4], bfW[4];                                               \
        _Pragma("unroll")                                                           \
        for (int i = 0; i < 4; ++i)                                                 \
            af[i] = *(const bf16x8*)(As + (p) + au + i * 512);                      \
        _Pragma("unroll")                                                           \
        for (int j = 0; j < 4; ++j) {                                               \
            bfU[j] = *(const bf16x8*)(Us + (p) + bu + j * 512);                     \
            bfW[j] = *(const bf16x8*)(Ws + (p) + bu + j * 512);                     \
        }                                                                           \
        __builtin_amdgcn_s_setprio(1);                                              \
        _Pragma("unroll")                                                           \
        for (int i = 0; i < 4; ++i)                                                 \
            _Pragma("unroll")                                                       \
            for (int j = 0; j < 4; ++j) {                                           \
                aS[i][j] = __builtin_amdgcn_mfma_f32_16x16x32_bf16(af[i], bfU[j], aS[i][j], 0, 0, 0); \
                aG[i][j] = __builtin_amdgcn_mfma_f32_16x16x32_bf16(af[i], bfW[j], aG[i][j], 0, 0, 0); \
            }                                                                       \
        __builtin_amdgcn_s_setprio(0);                                              \
    }

#define WAITV(n) asm volatile("s_waitcnt vmcnt(" #n ")" ::: "memory")
#define WAITL    asm volatile("s_waitcnt lgkmcnt(0)" ::: "memory")
#define BAR      __builtin_amdgcn_s_barrier()

    // prologue: tiles 0,1 in flight (12 outstanding GLLs per thread)
    STAGE(0)
    STAGE(1)

    // main loop: kt = 0..20 (7 x 3, buffers cycle 0,1,2; stage kt+2 each step).
    // WAITV(12): my 6 oldest outstanding loads (= tile kt) are done; tiles kt+1,kt+2
    // (12 loads) remain in flight across both barriers.  B1: everyone's tile-kt data
    // is in LDS.  WAITL+B2: everyone's ds_reads of this buffer drained -> buffer free.
    for (int i = 0; i < 7; ++i) {
        STAGE(2) WAITV(12); BAR; COMPUTE(0)      WAITL; BAR;
        STAGE(0) WAITV(12); BAR; COMPUTE(4096)   WAITL; BAR;
        STAGE(1) WAITV(12); BAR; COMPUTE(8192)   WAITL; BAR;
    }
    // kt=21: last stage (tile 23 -> buf2)
    STAGE(2) WAITV(12); BAR; COMPUTE(0)      WAITL; BAR;
    // kt=22: drain to 6 (tile 23 still in flight)
    WAITV(6); BAR; COMPUTE(4096)             WAITL; BAR;
    // kt=23: final tile
    WAITV(0); BAR; COMPUTE(8192)
#undef COMPUTE
#undef STAGE

    // epilogue: acc[i][j][rr] -> (y = n0+wn+j*16+ln, l = m0+wm+i*16+qd*4+rr)
    #pragma unroll
    for (int j = 0; j < 4; ++j) {
        const int y = n0 + wn + j * 16 + ln;
        float rs = 0.f, ys = 0.f;
        #pragma unroll
        for (int i = 0; i < 4; ++i) {
            #pragma unroll
            for (int rr = 0; rr < 4; ++rr) {
                float e = __expf(aS[i][j][rr]);
                rs += e;
                ys += e * aG[i][j][rr];
            }
        }
        rs += __shfl_xor(rs, 16, 64);  ys += __shfl_xor(ys, 16, 64);
        rs += __shfl_xor(rs, 32, 64);  ys += __shfl_xor(ys, 32, 64);
        if (qd == 0) {
            atomicAdd(&rowsum[y], rs);
            atomicAdd(&ynum[y], ys);
        }
    }
}

// -------- finalize: y = ynum/rowsum + bias (writeback), CE loss over y --------
// one block per batch; partial NLLs combined via atomicAdd into out0 (zeroed in launch)
__global__ __launch_bounds__(256) void ce_loss_k(const float* __restrict__ ynum,
                                                 const float* __restrict__ rowsum,
                                                 const float* __restrict__ fb,
                                                 const int* __restrict__ tgt,
                                                 float* __restrict__ out0,
                                                 float* __restrict__ yv) {
    __shared__ float smx[4], ssum[4], stv[4];
    const int b = blockIdx.x;
    const int t = threadIdx.x;
    const int wave = t >> 6, lane = t & 63;
    const float* yn = ynum + b * YY;
    const float* rsm = rowsum + b * YY;
    float* row = yv + b * YY;
    const int tg = tgt[b];
    float v[8];
    float mx = -3.0e38f;
    float tv = 0.f;
    #pragma unroll
    for (int i = 0; i < 8; ++i) {
        const int idx = t + 256 * i;
        v[i] = yn[idx] / rsm[idx] + fb[idx];
        row[idx] = v[i];                    // write final y
        mx = fmaxf(mx, v[i]);
        if (idx == tg) tv = v[i];
    }
    // block-reduce max
    #pragma unroll
    for (int o = 32; o; o >>= 1) mx = fmaxf(mx, __shfl_xor(mx, o, 64));
    if (lane == 0) smx[wave] = mx;
    __syncthreads();
    mx = fmaxf(fmaxf(smx[0], smx[1]), fmaxf(smx[2], smx[3]));
    float s = 0.f;
    #pragma unroll
    for (int i = 0; i < 8; ++i) s += __expf(v[i] - mx);
    #pragma unroll
    for (int o = 32; o; o >>= 1) { s += __shfl_xor(s, o, 64); tv += __shfl_xor(tv, o, 64); }
    if (lane == 0) { ssum[wave] = s; stv[wave] = tv; }
    __syncthreads();
    if (t == 0) {
        float st = ssum[0] + ssum[1] + ssum[2] + ssum[3];
        float tt = stv[0] + stv[1] + stv[2] + stv[3];
        atomicAdd(out0, (mx + logf(st) - tt) * 0.125f);
    }
}

extern "C" void kernel_launch(void* const* d_in, const int* in_sizes, int n_in,
                              void* d_out, int out_size, void* d_ws, size_t ws_size,
                              hipStream_t stream) {
    const float* x   = (const float*)d_in[0];   // (B,L,D)
    const float* Uw  = (const float*)d_in[1];   // (Y,D)
    const float* fw  = (const float*)d_in[2];   // (Y,D)
    const float* fb  = (const float*)d_in[3];   // (Y,)
    const int*   tgt = (const int*)d_in[4];     // (B,)
    float* out = (float*)d_out;                 // [loss, y(B*Y)]

    char* ws = (char*)d_ws;
    u16*  x16  = (u16*)(ws);                          // B*L*D bf16 = 50,331,648 B
    u16*  U16  = (u16*)(ws + 50331648);               // Y*D bf16   =  3,145,728 B
    u16*  fw16 = (u16*)(ws + 53477376);               // Y*D bf16   =  3,145,728 B
    float* rowsum = (float*)(ws + 56623104);          // B*Y fp32   =     65,536 B
    float* ynum   = (float*)(ws + 56688640);          // B*Y fp32   =     65,536 B

    hipMemsetAsync(rowsum, 0, 2 * (size_t)BB * YY * sizeof(float), stream);  // rowsum+ynum
    hipMemsetAsync(out, 0, sizeof(float), stream);                           // loss accumulator
    cast_w_k<<<1536, 256, 0, stream>>>(Uw, U16);
    cast_w_k<<<1536, 256, 0, stream>>>(fw, fw16);
    cast_x_k<<<(BB * LL * DD) / 1024, 256, 0, stream>>>(x, x16);

    // Fused S/G GEMM + exp + reductions: 4096 blocks (128l x 128y tiles),
    // L2-resident-weights order
    fused_k<<<(LL / 128) * (YY / 128) * BB, 256, 0, stream>>>(x16, U16, fw16, rowsum, ynum);

    ce_loss_k<<<BB, 256, 0, stream>>>(ynum, rowsum, fb, tgt, out, out + 1);
}